// Round 1
// baseline (198.216 us; speedup 1.0000x reference)
//
#include <hip/hip_runtime.h>
#include <math.h>

#define BS   32
#define NA   8400
#define NMAX 64
#define NC   80
#define TOPKN 13
#define ICAP 1024   // in-gt candidate cap; physical max ~400 (gt wh <= 128 on 640^2)
#define PCAP 512    // positive (align>0) cap; 2 regs/thread @ 256 thr

// out layout (floats)
#define OFF_LABELS 0
#define OFF_BBOX   (BS*NA)                 // 268800
#define OFF_SCORES (BS*NA + BS*NA*4)       // 1344000
#define OFF_FG     (BS*NA*5 + BS*NA*NC)    // 22848000
#define OFF_TGT    (BS*NA*6 + BS*NA*NC)    // 23116800

__device__ __forceinline__ float ciou_f(float g0, float g1, float g2, float g3,
                                        float p0, float p1, float p2, float p3) {
    const float eps = 1e-7f;
    float w1 = g2 - g0, h1 = g3 - g1;
    float w2 = p2 - p0, h2 = p3 - p1;
    float iw = fmaxf(fminf(g2, p2) - fmaxf(g0, p0), 0.f);
    float ih = fmaxf(fminf(g3, p3) - fmaxf(g1, p1), 0.f);
    float inter = iw * ih;
    float uni = w1 * h1 + w2 * h2 - inter + eps;
    float iou = inter / uni;
    float cw = fmaxf(g2, p2) - fminf(g0, p0);
    float ch = fmaxf(g3, p3) - fminf(g1, p1);
    float c2 = cw * cw + ch * ch + eps;
    float dx = p0 + p2 - g0 - g2;
    float dy = p1 + p3 - g1 - g3;
    float rho2 = (dx * dx + dy * dy) * 0.25f;
    const float four_over_pi2 = 4.0f / 9.869604401089358f;
    float dv = atanf(w2 / h2) - atanf(w1 / h1);
    float v = four_over_pi2 * dv * dv;
    float a = v / (v - iou + (1.0f + eps));
    return iou - (rho2 / c2 + v * a);
}

__device__ __forceinline__ float pow6f(float x) { float x2 = x * x; return x2 * x2 * x2; }

// ONE code path for align so all recomputations match.
__device__ __forceinline__ float align_at(int a, float g0, float g1, float g2, float g3,
                                          int label, const float* __restrict__ anc,
                                          const float* __restrict__ pb,
                                          const float* __restrict__ ps, float& d_out) {
    float ax = anc[a * 2 + 0], ay = anc[a * 2 + 1];
    float d = fminf(fminf(ax - g0, ay - g1), fminf(g2 - ax, g3 - ay));
    d_out = d;
    float al = 0.f;
    if (d > 1e-9f) {
        float p0 = pb[a * 4 + 0], p1 = pb[a * 4 + 1];
        float p2 = pb[a * 4 + 2], p3 = pb[a * 4 + 3];
        float cv = fmaxf(ciou_f(g0, g1, g2, g3, p0, p1, p2, p3), 0.f);
        if (cv > 0.f) al = ps[a * NC + label] * pow6f(cv);
    }
    return al;
}

// Phase A per (b,j):
//   pass1: d-only scan, compact in-gt anchors
//   pass2: dense CIoU -> positives (value,index)
//   P<=13: claim all; else 13 register-resident argmax passes (value desc, index asc)
//   zero-tail: PARALLEL rank of lowest-index zero entries over anchors [0,256)
// claim_count and gt_max are pre-zeroed by a small memset before this kernel.
__global__ __launch_bounds__(256) void kernA(const float* __restrict__ pd_scores,
                                             const float* __restrict__ pd_bboxes,
                                             const float* __restrict__ anc,
                                             const int*   __restrict__ gt_labels,
                                             const float* __restrict__ gt_bboxes,
                                             const float* __restrict__ mask_gt,
                                             int* __restrict__ claim_count,
                                             int* __restrict__ claimed_j,
                                             float* __restrict__ claimed_val) {
    const int j = blockIdx.x, b = blockIdx.y;
    const int tid = threadIdx.x;
    const int wid = tid >> 6, lane = tid & 63;

    __shared__ int   s_in[ICAP];
    __shared__ float s_pv[PCAP];
    __shared__ int   s_pi[PCAP];
    __shared__ int   s_icnt, s_pcnt;
    __shared__ float s_rv[4];
    __shared__ int   s_ri[4];
    __shared__ int   s_wz[4];

    if (mask_gt[b * NMAX + j] == 0.f) return;  // block-uniform exit

    if (tid == 0) { s_icnt = 0; s_pcnt = 0; }
    __syncthreads();

    const int   label = gt_labels[b * NMAX + j];
    const float g0 = gt_bboxes[(b * NMAX + j) * 4 + 0];
    const float g1 = gt_bboxes[(b * NMAX + j) * 4 + 1];
    const float g2 = gt_bboxes[(b * NMAX + j) * 4 + 2];
    const float g3 = gt_bboxes[(b * NMAX + j) * 4 + 3];
    const float* pb = pd_bboxes + (size_t)b * NA * 4;
    const float* ps = pd_scores + (size_t)b * NA * NC;
    const float2* anc2 = (const float2*)anc;

    // pass 1: cheap in-gt test only
    for (int a = tid; a < NA; a += 256) {
        float2 A = anc2[a];
        float d = fminf(fminf(A.x - g0, A.y - g1), fminf(g2 - A.x, g3 - A.y));
        if (d > 1e-9f) {
            int s = atomicAdd(&s_icnt, 1);
            if (s < ICAP) s_in[s] = a;
        }
    }
    __syncthreads();
    const int M = min(s_icnt, ICAP);

    // pass 2: dense CIoU over in-gt candidates
    for (int t = tid; t < M; t += 256) {
        int a = s_in[t];
        float p0 = pb[a * 4 + 0], p1 = pb[a * 4 + 1];
        float p2 = pb[a * 4 + 2], p3 = pb[a * 4 + 3];
        float cv = fmaxf(ciou_f(g0, g1, g2, g3, p0, p1, p2, p3), 0.f);
        if (cv > 0.f) {
            float al = ps[a * NC + label] * pow6f(cv);
            int s = atomicAdd(&s_pcnt, 1);
            if (s < PCAP) { s_pv[s] = al; s_pi[s] = a; }
        }
    }
    __syncthreads();
    const int P = min(s_pcnt, PCAP);
    int K1;

    if (P <= TOPKN) {
        K1 = P;
        if (tid < P) {
            int a = s_pi[tid];
            atomicAdd(&claim_count[b * NA + a], 1);
            claimed_j[b * NA + a] = j;          // unique-use when count==1
            claimed_val[b * NA + a] = s_pv[tid];
        }
    } else {
        K1 = TOPKN;
        // register-resident candidates: 2 per thread covers PCAP=512
        float v0 = -2.f, v1 = -2.f; int i0 = NA, i1 = NA;
        if (tid < P)       { v0 = s_pv[tid];       i0 = s_pi[tid]; }
        if (tid + 256 < P) { v1 = s_pv[tid + 256]; i1 = s_pi[tid + 256]; }
        for (int k = 0; k < TOPKN; k++) {
            float bv = v0; int bi = i0;
            if (v1 > bv || (v1 == bv && i1 < bi)) { bv = v1; bi = i1; }
            #pragma unroll
            for (int off = 32; off >= 1; off >>= 1) {
                float v2 = __shfl_down(bv, off, 64);
                int   i2 = __shfl_down(bi, off, 64);
                if (v2 > bv || (v2 == bv && i2 < bi)) { bv = v2; bi = i2; }
            }
            if (lane == 0) { s_rv[wid] = bv; s_ri[wid] = bi; }
            __syncthreads();
            float fv = s_rv[0]; int fi = s_ri[0];
            #pragma unroll
            for (int w = 1; w < 4; w++) {
                float v2 = s_rv[w]; int i2 = s_ri[w];
                if (v2 > fv || (v2 == fv && i2 < fi)) { fv = v2; fi = i2; }
            }
            if (i0 == fi) v0 = -1.f;   // winner self-clears (indices unique)
            if (i1 == fi) v1 = -1.f;
            if (tid == k) {
                atomicAdd(&claim_count[b * NA + fi], 1);
                claimed_j[b * NA + fi] = j;
                claimed_val[b * NA + fi] = fv;
            }
            __syncthreads();           // protect s_rv reuse next pass
        }
    }

    // zero-tail: top_k fills remaining picks with the lowest-index zero entries;
    // parallel rank over anchors [0,256) (zeros ubiquitous -> nearly always enough).
    if (K1 < TOPKN) {
        const int need = TOPKN - K1;
        float d;
        float al = align_at(tid, g0, g1, g2, g3, label, anc, pb, ps, d);
        bool z = (al == 0.f);
        unsigned long long m = __ballot(z);
        int lanerank = __popcll(m & ((1ull << lane) - 1ull));
        if (lane == 0) s_wz[wid] = __popcll(m);
        __syncthreads();
        int base = 0, nz = 0;
        #pragma unroll
        for (int w = 0; w < 4; w++) { if (w < wid) base += s_wz[w]; nz += s_wz[w]; }
        int rank = base + lanerank;
        if (z && rank < need && d > 1e-9f) {
            atomicAdd(&claim_count[b * NA + tid], 1);
            claimed_j[b * NA + tid] = j;
            claimed_val[b * NA + tid] = 0.f;
        }
        // fallback (practically unreachable): fewer than `need` zeros in [0,256)
        if (tid == 0 && nz < need) {
            int rem = need - nz;
            for (int a = 256; a < NA && rem > 0; a++) {
                float dd;
                float a2 = align_at(a, g0, g1, g2, g3, label, anc, pb, ps, dd);
                if (a2 == 0.f) {
                    if (dd > 1e-9f) {
                        atomicAdd(&claim_count[b * NA + a], 1);
                        claimed_j[b * NA + a] = j;
                        claimed_val[b * NA + a] = 0.f;
                    }
                    rem--;
                }
            }
        }
    }
}

// Phase B: resolve assignment, per-gt max, scalar outputs.
// Also writes this block's 256 score rows as dense zeros (coalesced float4),
// replacing the former 86 MB memset; kernD scatters values on top afterwards.
__global__ __launch_bounds__(256) void kernB(const float* __restrict__ pd_scores,
                                             const float* __restrict__ pd_bboxes,
                                             const float* __restrict__ anc,
                                             const int*   __restrict__ gt_labels,
                                             const float* __restrict__ gt_bboxes,
                                             const float* __restrict__ mask_gt,
                                             const int* __restrict__ claim_count,
                                             const int* __restrict__ claimed_j,
                                             const float* __restrict__ claimed_val,
                                             int* __restrict__ assigned_j,
                                             float* __restrict__ assigned_align,
                                             unsigned int* __restrict__ gt_max,
                                             float* __restrict__ out) {
    // dense zero of this block's 256 score rows: 256*NC floats = 5120 float4,
    // 20 per thread, block-contiguous -> fully coalesced (grid is exact: 1050*256 == BS*NA)
    {
        float4 z = make_float4(0.f, 0.f, 0.f, 0.f);
        float4* dst = (float4*)(out + OFF_SCORES) + (size_t)blockIdx.x * (256 * NC / 4);
        #pragma unroll
        for (int k = 0; k < (256 * NC / 4) / 256; k++)
            dst[threadIdx.x + k * 256] = z;
    }

    int idx = blockIdx.x * blockDim.x + threadIdx.x;
    if (idx >= BS * NA) return;
    int b = idx / NA, a = idx - b * NA;

    int cnt = claim_count[idx];
    int ja = -1;

    if (cnt > 0) {
        float val;
        if (cnt == 1) {
            ja  = claimed_j[idx];
            val = claimed_val[idx];   // unique writer when cnt==1
        } else {
            float ax = anc[a * 2 + 0], ay = anc[a * 2 + 1];
            float p0 = pd_bboxes[((size_t)b * NA + a) * 4 + 0];
            float p1 = pd_bboxes[((size_t)b * NA + a) * 4 + 1];
            float p2 = pd_bboxes[((size_t)b * NA + a) * 4 + 2];
            float p3 = pd_bboxes[((size_t)b * NA + a) * 4 + 3];
            // argmax_j overlaps (first max), overlaps = m ? clip0(ciou) : 0
            float best = -1.f; ja = 0;
            for (int j = 0; j < NMAX; j++) {
                float mgj = mask_gt[b * NMAX + j];
                float ov = 0.f;
                if (mgj != 0.f) {
                    float g0 = gt_bboxes[(b * NMAX + j) * 4 + 0];
                    float g1 = gt_bboxes[(b * NMAX + j) * 4 + 1];
                    float g2 = gt_bboxes[(b * NMAX + j) * 4 + 2];
                    float g3 = gt_bboxes[(b * NMAX + j) * 4 + 3];
                    float d = fminf(fminf(ax - g0, ay - g1), fminf(g2 - ax, g3 - ay));
                    if (d > 1e-9f)
                        ov = fmaxf(ciou_f(g0, g1, g2, g3, p0, p1, p2, p3), 0.f);
                }
                if (ov > best) { best = ov; ja = j; }
            }
            // align_metric at (ja, a) with mask applied
            val = 0.f;
            float mgj = mask_gt[b * NMAX + ja];
            if (mgj != 0.f) {
                float g0 = gt_bboxes[(b * NMAX + ja) * 4 + 0];
                float g1 = gt_bboxes[(b * NMAX + ja) * 4 + 1];
                float g2 = gt_bboxes[(b * NMAX + ja) * 4 + 2];
                float g3 = gt_bboxes[(b * NMAX + ja) * 4 + 3];
                float d = fminf(fminf(ax - g0, ay - g1), fminf(g2 - ax, g3 - ay));
                if (d > 1e-9f) {
                    float cv = fmaxf(ciou_f(g0, g1, g2, g3, p0, p1, p2, p3), 0.f);
                    if (cv > 0.f) {
                        int lab = gt_labels[b * NMAX + ja];
                        val = pd_scores[((size_t)b * NA + a) * NC + lab] * pow6f(cv);
                    }
                }
            }
        }
        assigned_align[idx] = val;
        atomicMax(&gt_max[b * NMAX + ja], __float_as_uint(val));  // val>=0: uint order == float order
    }
    assigned_j[idx] = ja;  // -1 for unclaimed (kernD gate)

    // scalar outputs for ALL anchors
    int fg = (cnt > 0);
    int tgt = fg ? ja : 0;
    out[OFF_LABELS + idx] = (float)gt_labels[b * NMAX + tgt];
    const float4 bb = *(const float4*)&gt_bboxes[(b * NMAX + tgt) * 4];
    *(float4*)&out[OFF_BBOX + idx * 4] = bb;
    out[OFF_FG + idx]  = fg ? 1.f : 0.f;
    out[OFF_TGT + idx] = (float)tgt;
}

// Phase D: scatter normalized scores for fg anchors (rows zeroed by kernB).
__global__ __launch_bounds__(256) void kernD(const int* __restrict__ gt_labels,
                                             const int* __restrict__ assigned_j,
                                             const float* __restrict__ assigned_align,
                                             const unsigned int* __restrict__ gt_max,
                                             float* __restrict__ out) {
    int idx = blockIdx.x * blockDim.x + threadIdx.x;
    if (idx >= BS * NA) return;
    int ja = assigned_j[idx];
    if (ja < 0) return;
    int b = idx / NA;
    float v = assigned_align[idx];
    float dyn = 0.4f * __uint_as_float(gt_max[b * NMAX + ja]);
    float sc = v / (dyn + 1e-9f);
    int lab = gt_labels[b * NMAX + ja];
    out[OFF_SCORES + (size_t)idx * NC + lab] = sc;
}

extern "C" void kernel_launch(void* const* d_in, const int* in_sizes, int n_in,
                              void* d_out, int out_size, void* d_ws, size_t ws_size,
                              hipStream_t stream) {
    const float* pd_scores = (const float*)d_in[0];
    const float* pd_bboxes = (const float*)d_in[1];
    const float* anc       = (const float*)d_in[2];
    const int*   gt_labels = (const int*)d_in[3];
    const float* gt_bboxes = (const float*)d_in[4];
    const float* mask_gt   = (const float*)d_in[5];
    float* out = (float*)d_out;

    char* ws = (char*)d_ws;
    size_t off = 0;
    int*          claim_count    = (int*)(ws + off);           off += (size_t)BS * NA * 4;
    unsigned int* gt_max         = (unsigned int*)(ws + off);  off += (size_t)BS * NMAX * 4;
    int*          claimed_j      = (int*)(ws + off);           off += (size_t)BS * NA * 4;
    float*        claimed_val    = (float*)(ws + off);         off += (size_t)BS * NA * 4;
    int*          assigned_j     = (int*)(ws + off);           off += (size_t)BS * NA * 4;
    float*        assigned_align = (float*)(ws + off);         off += (size_t)BS * NA * 4;

    // small fill: zeroes claim_count + gt_max (contiguous, ~1.06 MB) each launch
    hipMemsetAsync(ws, 0, (size_t)(BS * NA + BS * NMAX) * 4, stream);

    kernA<<<dim3(NMAX, BS), 256, 0, stream>>>(pd_scores, pd_bboxes, anc, gt_labels,
                                              gt_bboxes, mask_gt, claim_count, claimed_j,
                                              claimed_val);
    int nanch = BS * NA;
    kernB<<<(nanch + 255) / 256, 256, 0, stream>>>(pd_scores, pd_bboxes, anc, gt_labels,
                                                   gt_bboxes, mask_gt, claim_count, claimed_j,
                                                   claimed_val, assigned_j, assigned_align,
                                                   gt_max, out);
    kernD<<<(nanch + 255) / 256, 256, 0, stream>>>(gt_labels, assigned_j, assigned_align,
                                                   gt_max, out);
}